// Round 1
// baseline (877.114 us; speedup 1.0000x reference)
//
#include <hip/hip_runtime.h>

#define TOK  10560
#define CIMG 3072
#define KHD  1024

typedef unsigned short ushort_t;
using bf16x8 = __attribute__((ext_vector_type(8))) __bf16;
using f32x4  = __attribute__((ext_vector_type(4))) float;

static __device__ __forceinline__ unsigned short f2bf(float f){
  union { float f; unsigned u; } x; x.f = f;
  unsigned r = x.u + 0x7fffu + ((x.u >> 16) & 1u);
  return (unsigned short)(r >> 16);
}
static __device__ __forceinline__ float bf2f(unsigned short u){
  union { unsigned u; float f; } x; x.u = ((unsigned)u) << 16; return x.f;
}
static __device__ __forceinline__ float wave_sum(float v){
  #pragma unroll
  for (int off = 32; off > 0; off >>= 1) v += __shfl_xor(v, off, 64);
  return v;
}

// ---------------- conditioning MLP: emb rows 72..87 (cond rows 64..79) -------
__global__ void k_pre(const float* __restrict__ cond,
                      const float* __restrict__ w1, const float* __restrict__ b1,
                      const float* __restrict__ w2, const float* __restrict__ b2,
                      float* __restrict__ emb){
  __shared__ float cs[16][16];
  __shared__ float h1[16][512];
  int t = threadIdx.x;
  if (t < 256) cs[t >> 4][t & 15] = cond[(64 + (t >> 4)) * 16 + (t & 15)];
  __syncthreads();
  #pragma unroll
  for (int i = 0; i < 8; ++i){
    int idx = t + i * 1024; int r = idx >> 9, c = idx & 511;
    float s = b1[c];
    #pragma unroll
    for (int j = 0; j < 16; ++j) s += cs[r][j] * w1[j * 512 + c];
    h1[r][c] = s / (1.f + __expf(-s));   // silu
  }
  __syncthreads();
  #pragma unroll
  for (int i = 0; i < 8; ++i){
    int idx = t + i * 1024; int r = idx >> 9, c = idx & 511;
    float e = b2[c];
    for (int j = 0; j < 512; ++j) e += h1[r][j] * w2[j * 512 + c];
    emb[idx] = e;
  }
}

// ---------------- kv = mf @ kv_w, split-K partials (deterministic) ----------
__global__ __launch_bounds__(256) void k_kv(const float* __restrict__ emb,
                                            const float* __restrict__ kvw,
                                            float* __restrict__ part){
  int bl = blockIdx.x;                 // 3 l * 8 ntile * 16 kchunk = 384
  int l = bl / 128, rem = bl % 128, nt = rem / 16, kc = rem % 16;
  int n = nt * 256 + threadIdx.x;
  const float* e = emb + 2048 * l + kc * 256;   // mf[l][r] = emb[2048l + r]
  const float* w = kvw + (size_t)(kc * 256) * 2048 + n;
  float acc = 0.f;
  for (int r = 0; r < 256; ++r) acc += e[r] * w[(size_t)r * 2048];
  part[kc * 6144 + l * 2048 + n] = acc;
}

// ---------------- reduce partials, bias, k-RMSNorm ---------------------------
__global__ void k_knorm(const float* __restrict__ part, const float* __restrict__ kvb,
                        const float* __restrict__ knw, float* __restrict__ kn,
                        float* __restrict__ vv){
  int wid = threadIdx.x >> 6, lane = threadIdx.x & 63;
  for (int i = 0; i < 12; ++i){
    int g = wid * 12 + i;               // 0..47 = (l,h)
    int l = g >> 4, h = g & 15;
    int ik = l * 2048 + h * 64 + lane;
    float kk = kvb[h * 64 + lane];
    float v  = kvb[1024 + h * 64 + lane];
    for (int p = 0; p < 16; ++p){ kk += part[p * 6144 + ik]; v += part[p * 6144 + ik + 1024]; }
    float ss = wave_sum(kk * kk);
    kn[l * 1024 + h * 64 + lane] = kk * rsqrtf(ss * (1.f/64.f) + 1e-6f) * knw[lane];
    vv[l * 1024 + h * 64 + lane] = v;
  }
}

// ---------------- transpose + f32->bf16 weight convert: dst[C][R] ------------
__global__ __launch_bounds__(256) void k_tconv(const float* __restrict__ src,
                                               ushort_t* __restrict__ dst,
                                               int R, int C){
  __shared__ float tile[32][33];
  int nTr = R >> 5;
  int tr = blockIdx.x % nTr, tc = blockIdx.x / nTr;
  int r0 = tr * 32, c0 = tc * 32, t = threadIdx.x;
  #pragma unroll
  for (int i = 0; i < 4; ++i){
    int idx = t + i * 256; int r = idx >> 5, c = idx & 31;
    tile[r][c] = src[(size_t)(r0 + r) * C + c0 + c];
  }
  __syncthreads();
  #pragma unroll
  for (int i = 0; i < 4; ++i){
    int idx = t + i * 256; int rr = idx >> 5, cc = idx & 31;
    dst[(size_t)(c0 + rr) * R + r0 + cc] = f2bf(tile[cc][rr]);
  }
}

// ---------------- 128x128 bf16 MFMA GEMM, B^T layout, dbuf LDS ---------------
// EPI 0: out bf16 = acc + bias.  EPI 1: out f32 = acc + bias + resid.
template<bool AF32, int EPI>
__global__ __launch_bounds__(256) void gemm_bt(
    const void* __restrict__ Aptr, const ushort_t* __restrict__ Bt,
    int Mdim, int Kdim, int Ndim,
    const float* __restrict__ bias, const float* __restrict__ resid,
    void* __restrict__ outp){
  const int tid = threadIdx.x;
  const int lane = tid & 63, wid = tid >> 6;
  const int wr = wid >> 1, wc = wid & 1;
  const int l15 = lane & 15, kg = lane >> 4;
  const int ntiles = Ndim >> 7;
  const int mt = blockIdx.x / ntiles, nt = blockIdx.x % ntiles;
  const int mbase = mt << 7, nbase = nt << 7;

  __shared__ __align__(16) unsigned char lds[32768]; // 2 bufs x (A 8K + B 8K)

  const int srow = tid >> 1;      // 0..127
  const int sh   = tid & 1;       // k-half (16 elems)
  int agrow = mbase + srow; if (agrow > Mdim - 1) agrow = Mdim - 1;

  const float*    Af = (const float*)Aptr;
  const ushort_t* Ab = (const ushort_t*)Aptr;

  f32x4 acc[4][4];
  #pragma unroll
  for (int m = 0; m < 4; ++m)
    #pragma unroll
    for (int n = 0; n < 4; ++n) acc[m][n] = {0.f, 0.f, 0.f, 0.f};

  const int ksteps = Kdim >> 5;

  float4 avf[4];
  uint4  avb[2];
  uint4  bvb[2];

  auto load_stage = [&](int ks){
    int kb = ks << 5;
    if (AF32){
      const float* p = Af + (size_t)agrow * Kdim + kb + sh * 16;
      #pragma unroll
      for (int i = 0; i < 4; ++i) avf[i] = *(const float4*)(p + i * 4);
    } else {
      const ushort_t* p = Ab + (size_t)agrow * Kdim + kb + sh * 16;
      #pragma unroll
      for (int s = 0; s < 2; ++s) avb[s] = *(const uint4*)(p + s * 8);
    }
    const ushort_t* q = Bt + (size_t)(nbase + srow) * Kdim + kb + sh * 16;
    #pragma unroll
    for (int s = 0; s < 2; ++s) bvb[s] = *(const uint4*)(q + s * 8);
  };

  // LDS layout: [kslot 0..3][row 0..127][16B]  -> conflict-free b128 frag reads
  auto store_stage = [&](int buf){
    unsigned char* base = lds + buf * 16384;
    if (AF32){
      #pragma unroll
      for (int i = 0; i < 4; ++i){
        unsigned lo = (unsigned)f2bf(avf[i].x) | ((unsigned)f2bf(avf[i].y) << 16);
        unsigned hi = (unsigned)f2bf(avf[i].z) | ((unsigned)f2bf(avf[i].w) << 16);
        int slot = sh * 2 + (i >> 1);
        *(uint2*)(base + slot * 2048 + srow * 16 + (i & 1) * 8) = (uint2){lo, hi};
      }
    } else {
      #pragma unroll
      for (int s = 0; s < 2; ++s)
        *(uint4*)(base + (sh * 2 + s) * 2048 + srow * 16) = avb[s];
    }
    #pragma unroll
    for (int s = 0; s < 2; ++s)
      *(uint4*)(base + 8192 + (sh * 2 + s) * 2048 + srow * 16) = bvb[s];
  };

  load_stage(0);
  store_stage(0);
  __syncthreads();

  for (int ks = 0; ks < ksteps; ++ks){
    const int cur = ks & 1;
    if (ks + 1 < ksteps) load_stage(ks + 1);

    const unsigned char* pa = lds + cur * 16384 + kg * 2048;
    const unsigned char* pb = pa + 8192;
    bf16x8 afr[4], bfr[4];
    #pragma unroll
    for (int m = 0; m < 4; ++m) afr[m] = *(const bf16x8*)(pa + (wr*64 + m*16 + l15) * 16);
    #pragma unroll
    for (int n = 0; n < 4; ++n) bfr[n] = *(const bf16x8*)(pb + (wc*64 + n*16 + l15) * 16);
    #pragma unroll
    for (int m = 0; m < 4; ++m)
      #pragma unroll
      for (int n = 0; n < 4; ++n)
        acc[m][n] = __builtin_amdgcn_mfma_f32_16x16x32_bf16(afr[m], bfr[n], acc[m][n], 0, 0, 0);

    if (ks + 1 < ksteps) store_stage((ks + 1) & 1);
    __syncthreads();
  }

  #pragma unroll
  for (int n = 0; n < 4; ++n){
    int col = nbase + wc * 64 + n * 16 + l15;
    float bb = bias[col];
    #pragma unroll
    for (int m = 0; m < 4; ++m){
      #pragma unroll
      for (int j = 0; j < 4; ++j){
        int row = mbase + wr * 64 + m * 16 + kg * 4 + j;
        if (row < Mdim){
          float v = acc[m][n][j] + bb;
          if (EPI == 0){
            ((ushort_t*)outp)[(size_t)row * Ndim + col] = f2bf(v);
          } else {
            size_t o = (size_t)row * Ndim + col;
            ((float*)outp)[o] = v + resid[o];
          }
        }
      }
    }
  }
}

// ---------------- per-token attention over L=3 keys --------------------------
__global__ __launch_bounds__(256) void k_attn(const ushort_t* __restrict__ Qb,
    const float* __restrict__ kn, const float* __restrict__ vv,
    const float* __restrict__ qnw, ushort_t* __restrict__ Ob){
  int wid = threadIdx.x >> 6, lane = threadIdx.x & 63;
  int m = blockIdx.x * 4 + wid;           // grid 2640 * 4 waves = 10560 exact
  float qw = qnw[lane];
  const ushort_t* qrow = Qb + (size_t)m * 1024;
  ushort_t* orow = Ob + (size_t)m * 1024;
  for (int h = 0; h < 16; ++h){
    int ib = h * 64 + lane;
    float q = bf2f(qrow[ib]);
    float ss = wave_sum(q * q);
    float qn = q * rsqrtf(ss * (1.f/64.f) + 1e-6f) * qw;
    float s0 = wave_sum(qn * kn[ib]) * 0.125f;
    float s1 = wave_sum(qn * kn[1024 + ib]) * 0.125f;
    float s2 = wave_sum(qn * kn[2048 + ib]) * 0.125f;
    float mx = fmaxf(s0, fmaxf(s1, s2));
    float e0 = __expf(s0 - mx), e1 = __expf(s1 - mx), e2 = __expf(s2 - mx);
    float inv = 1.f / (e0 + e1 + e2);
    float o = (e0 * vv[ib] + e1 * vv[1024 + ib] + e2 * vv[2048 + ib]) * inv;
    orow[ib] = f2bf(o);
  }
}

extern "C" void kernel_launch(void* const* d_in, const int* in_sizes, int n_in,
                              void* d_out, int out_size, void* d_ws, size_t ws_size,
                              hipStream_t stream){
  const float* x    = (const float*)d_in[0];
  const float* cond = (const float*)d_in[1];
  const float* mew1 = (const float*)d_in[2];
  const float* meb1 = (const float*)d_in[3];
  const float* mew2 = (const float*)d_in[4];
  const float* meb2 = (const float*)d_in[5];
  const float* qw   = (const float*)d_in[6];
  const float* qb   = (const float*)d_in[7];
  const float* kvw  = (const float*)d_in[8];
  const float* kvb  = (const float*)d_in[9];
  const float* qnw  = (const float*)d_in[10];
  const float* knw  = (const float*)d_in[11];
  const float* ow   = (const float*)d_in[12];
  const float* ob   = (const float*)d_in[13];

  char* ws = (char*)d_ws;
  float*    emb    = (float*)(ws + 0);          // 16x512 f32
  float*    kvpart = (float*)(ws + 32768);      // 16x6144 f32
  float*    kn     = (float*)(ws + 425984);     // 3x1024 f32
  float*    vv     = (float*)(ws + 438272);     // 3x1024 f32
  ushort_t* qwt    = (ushort_t*)(ws + 450560);  // [1024][3072] bf16
  ushort_t* owt    = (ushort_t*)(ws + 6742016); // [3072][1024] bf16
  ushort_t* Qbuf   = (ushort_t*)(ws + 13033472);// [10560][1024] bf16
  ushort_t* Obuf   = (ushort_t*)(ws + 34660352);// [10560][1024] bf16

  k_pre<<<1, 1024, 0, stream>>>(cond, mew1, meb1, mew2, meb2, emb);
  k_kv<<<384, 256, 0, stream>>>(emb, kvw, kvpart);
  k_knorm<<<1, 256, 0, stream>>>(kvpart, kvb, knw, kn, vv);
  k_tconv<<<3072, 256, 0, stream>>>(qw, qwt, 3072, 1024);
  k_tconv<<<3072, 256, 0, stream>>>(ow, owt, 1024, 3072);
  gemm_bt<true, 0><<<83 * 8, 256, 0, stream>>>(x, qwt, TOK, CIMG, KHD, qb, nullptr, Qbuf);
  k_attn<<<2640, 256, 0, stream>>>(Qbuf, kn, vv, qnw, Obuf);
  gemm_bt<false, 1><<<83 * 24, 256, 0, stream>>>(Obuf, owt, TOK, KHD, CIMG, ob, x, d_out);
}

// Round 2
// 541.414 us; speedup vs baseline: 1.6200x; 1.6200x over previous
//
#include <hip/hip_runtime.h>

#define TOK  10560
#define CIMG 3072
#define KHD  1024

typedef unsigned short ushort_t;
typedef unsigned int u32;
using bf16x8 = __attribute__((ext_vector_type(8))) __bf16;
using f32x4  = __attribute__((ext_vector_type(4))) float;

#define GLD_LDS16(gp, lp) __builtin_amdgcn_global_load_lds( \
    (const __attribute__((address_space(1))) u32*)(gp), \
    (__attribute__((address_space(3))) u32*)(lp), 16, 0, 0)

static __device__ __forceinline__ unsigned short f2bf(float f){
  union { float f; unsigned u; } x; x.f = f;
  unsigned r = x.u + 0x7fffu + ((x.u >> 16) & 1u);
  return (unsigned short)(r >> 16);
}
static __device__ __forceinline__ float bf2f(unsigned short u){
  union { unsigned u; float f; } x; x.u = ((unsigned)u) << 16; return x.f;
}
static __device__ __forceinline__ float wave_sum(float v){
  #pragma unroll
  for (int off = 32; off > 0; off >>= 1) v += __shfl_xor(v, off, 64);
  return v;
}

// ---------------- conditioning MLP: emb rows 72..87 (cond rows 64..79) -------
__global__ void k_pre(const float* __restrict__ cond,
                      const float* __restrict__ w1, const float* __restrict__ b1,
                      const float* __restrict__ w2, const float* __restrict__ b2,
                      float* __restrict__ emb){
  __shared__ float cs[16][16];
  __shared__ float h1[16][512];
  int t = threadIdx.x;
  if (t < 256) cs[t >> 4][t & 15] = cond[(64 + (t >> 4)) * 16 + (t & 15)];
  __syncthreads();
  #pragma unroll
  for (int i = 0; i < 8; ++i){
    int idx = t + i * 1024; int r = idx >> 9, c = idx & 511;
    float s = b1[c];
    #pragma unroll
    for (int j = 0; j < 16; ++j) s += cs[r][j] * w1[j * 512 + c];
    h1[r][c] = s / (1.f + __expf(-s));   // silu
  }
  __syncthreads();
  #pragma unroll
  for (int i = 0; i < 8; ++i){
    int idx = t + i * 1024; int r = idx >> 9, c = idx & 511;
    float e = b2[c];
    for (int j = 0; j < 512; ++j) e += h1[r][j] * w2[j * 512 + c];
    emb[idx] = e;
  }
}

// ---------------- kv = mf @ kv_w, split-K partials (deterministic) ----------
__global__ __launch_bounds__(256) void k_kv(const float* __restrict__ emb,
                                            const float* __restrict__ kvw,
                                            float* __restrict__ part){
  int bl = blockIdx.x;                 // 3 l * 8 ntile * 16 kchunk = 384
  int l = bl / 128, rem = bl % 128, nt = rem / 16, kc = rem % 16;
  int n = nt * 256 + threadIdx.x;
  const float* e = emb + 2048 * l + kc * 256;   // mf[l][r] = emb[2048l + r]
  const float* w = kvw + (size_t)(kc * 256) * 2048 + n;
  float acc = 0.f;
  for (int r = 0; r < 256; ++r) acc += e[r] * w[(size_t)r * 2048];
  part[kc * 6144 + l * 2048 + n] = acc;
}

// ---------------- reduce partials, bias, k-RMSNorm ---------------------------
__global__ void k_knorm(const float* __restrict__ part, const float* __restrict__ kvb,
                        const float* __restrict__ knw, float* __restrict__ kn,
                        float* __restrict__ vv){
  int wid = threadIdx.x >> 6, lane = threadIdx.x & 63;
  for (int i = 0; i < 12; ++i){
    int g = wid * 12 + i;               // 0..47 = (l,h)
    int l = g >> 4, h = g & 15;
    int ik = l * 2048 + h * 64 + lane;
    float kk = kvb[h * 64 + lane];
    float v  = kvb[1024 + h * 64 + lane];
    for (int p = 0; p < 16; ++p){ kk += part[p * 6144 + ik]; v += part[p * 6144 + ik + 1024]; }
    float ss = wave_sum(kk * kk);
    kn[l * 1024 + h * 64 + lane] = kk * rsqrtf(ss * (1.f/64.f) + 1e-6f) * knw[lane];
    vv[l * 1024 + h * 64 + lane] = v;
  }
}

// ---------------- transpose + f32->bf16 weight convert: dst[C][R] ------------
__global__ __launch_bounds__(256) void k_tconv(const float* __restrict__ src,
                                               ushort_t* __restrict__ dst,
                                               int R, int C){
  __shared__ float tile[32][33];
  int nTr = R >> 5;
  int tr = blockIdx.x % nTr, tc = blockIdx.x / nTr;
  int r0 = tr * 32, c0 = tc * 32, t = threadIdx.x;
  #pragma unroll
  for (int i = 0; i < 4; ++i){
    int idx = t + i * 256; int r = idx >> 5, c = idx & 31;
    tile[r][c] = src[(size_t)(r0 + r) * C + c0 + c];
  }
  __syncthreads();
  #pragma unroll
  for (int i = 0; i < 4; ++i){
    int idx = t + i * 256; int rr = idx >> 5, cc = idx & 31;
    dst[(size_t)(c0 + rr) * R + r0 + cc] = f2bf(tile[cc][rr]);
  }
}

// ---------------- x f32 -> bf16 streaming convert ----------------------------
__global__ __launch_bounds__(256) void k_xconv(const float* __restrict__ x,
                                               ushort_t* __restrict__ xb, int n4){
  for (int i = blockIdx.x * 256 + threadIdx.x; i < n4; i += gridDim.x * 256){
    float4 v = ((const float4*)x)[i];
    ushort4 o;
    o.x = f2bf(v.x); o.y = f2bf(v.y); o.z = f2bf(v.z); o.w = f2bf(v.w);
    ((ushort4*)xb)[i] = o;
  }
}

// ---------------- 128x128 bf16 MFMA GEMM, m97 structure ----------------------
// A bf16 [M][K], Bt bf16 [N][K]. global_load_lds staging, linear LDS [row][64B],
// double-buffered, ONE barrier per K-step.
// EPI 0: out bf16 = acc + bias.  EPI 1: out f32 = acc + bias + resid.
template<int EPI>
__global__ __launch_bounds__(256) void gemm_lds(
    const ushort_t* __restrict__ A, const ushort_t* __restrict__ Bt,
    int Mdim, int Kdim, int Ndim,
    const float* __restrict__ bias, const float* __restrict__ resid,
    void* __restrict__ outp){
  __shared__ __align__(16) unsigned char lds[32768]; // 2 bufs x (A 8K + B 8K)
  const int tid = threadIdx.x;
  const int lane = tid & 63, wid = tid >> 6;
  const int wr = wid >> 1, wc = wid & 1;
  const int l15 = lane & 15, kg = lane >> 4;
  const int ntiles = Ndim >> 7;

  // XCD-aware swizzle (grids 664 / 1992 are both divisible by 8 -> bijective)
  int bid = blockIdx.x;
  const int cpx = gridDim.x >> 3;
  bid = (bid & 7) * cpx + (bid >> 3);
  const int mt = bid / ntiles, nt = bid % ntiles;
  const int mbase = mt << 7, nbase = nt << 7;

  // staging: per wave 2 A-loads + 2 B-loads; each load = 16 rows x 64B
  const int srow = wid * 32 + (lane >> 2);
  const int schunk = lane & 3;
  int ar0 = mbase + srow;      if (ar0 >= Mdim) ar0 = Mdim - 1;
  int ar1 = mbase + srow + 16; if (ar1 >= Mdim) ar1 = Mdim - 1;
  const ushort_t* gA0 = A  + (size_t)ar0 * Kdim + schunk * 8;
  const ushort_t* gA1 = A  + (size_t)ar1 * Kdim + schunk * 8;
  const ushort_t* gB0 = Bt + (size_t)(nbase + srow) * Kdim + schunk * 8;
  const ushort_t* gB1 = Bt + (size_t)(nbase + srow + 16) * Kdim + schunk * 8;
  unsigned char* ldsA0 = lds + (wid * 32) * 64;
  unsigned char* ldsA1 = lds + (wid * 32 + 16) * 64;
  unsigned char* ldsB0 = lds + 8192 + (wid * 32) * 64;
  unsigned char* ldsB1 = lds + 8192 + (wid * 32 + 16) * 64;

  auto stage = [&](int buf, int ks){
    const int kb = ks << 5;
    const int bo = buf * 16384;
    GLD_LDS16(gA0 + kb, ldsA0 + bo);
    GLD_LDS16(gA1 + kb, ldsA1 + bo);
    GLD_LDS16(gB0 + kb, ldsB0 + bo);
    GLD_LDS16(gB1 + kb, ldsB1 + bo);
  };

  f32x4 acc[4][4];
  #pragma unroll
  for (int m = 0; m < 4; ++m)
    #pragma unroll
    for (int n = 0; n < 4; ++n) acc[m][n] = {0.f, 0.f, 0.f, 0.f};

  const int ksteps = Kdim >> 5;

  stage(0, 0);
  __syncthreads();

  for (int ks = 0; ks < ksteps; ++ks){
    const int cur = ks & 1;
    if (ks + 1 < ksteps) stage(cur ^ 1, ks + 1);

    const unsigned char* pa = lds + cur * 16384 + kg * 16;
    const unsigned char* pb = pa + 8192;
    bf16x8 afr[4], bfr[4];
    #pragma unroll
    for (int m = 0; m < 4; ++m) afr[m] = *(const bf16x8*)(pa + (wr*64 + m*16 + l15) * 64);
    #pragma unroll
    for (int n = 0; n < 4; ++n) bfr[n] = *(const bf16x8*)(pb + (wc*64 + n*16 + l15) * 64);
    #pragma unroll
    for (int m = 0; m < 4; ++m)
      #pragma unroll
      for (int n = 0; n < 4; ++n)
        acc[m][n] = __builtin_amdgcn_mfma_f32_16x16x32_bf16(afr[m], bfr[n], acc[m][n], 0, 0, 0);

    __syncthreads();   // vmcnt(0)+lgkmcnt(0) drain: next buf staged, reads done
  }

  #pragma unroll
  for (int n = 0; n < 4; ++n){
    int col = nbase + wc * 64 + n * 16 + l15;
    float bb = bias[col];
    #pragma unroll
    for (int m = 0; m < 4; ++m){
      #pragma unroll
      for (int j = 0; j < 4; ++j){
        int row = mbase + wr * 64 + m * 16 + kg * 4 + j;
        if (row < Mdim){
          float v = acc[m][n][j] + bb;
          if (EPI == 0){
            ((ushort_t*)outp)[(size_t)row * Ndim + col] = f2bf(v);
          } else {
            size_t o = (size_t)row * Ndim + col;
            ((float*)outp)[o] = v + resid[o];
          }
        }
      }
    }
  }
}

// ---------------- per-token attention over L=3 keys --------------------------
__global__ __launch_bounds__(256) void k_attn(const ushort_t* __restrict__ Qb,
    const float* __restrict__ kn, const float* __restrict__ vv,
    const float* __restrict__ qnw, ushort_t* __restrict__ Ob){
  int wid = threadIdx.x >> 6, lane = threadIdx.x & 63;
  int m = blockIdx.x * 4 + wid;           // grid 2640 * 4 waves = 10560 exact
  float qw = qnw[lane];
  const ushort_t* qrow = Qb + (size_t)m * 1024;
  ushort_t* orow = Ob + (size_t)m * 1024;
  for (int h = 0; h < 16; ++h){
    int ib = h * 64 + lane;
    float q = bf2f(qrow[ib]);
    float ss = wave_sum(q * q);
    float qn = q * rsqrtf(ss * (1.f/64.f) + 1e-6f) * qw;
    float s0 = wave_sum(qn * kn[ib]) * 0.125f;
    float s1 = wave_sum(qn * kn[1024 + ib]) * 0.125f;
    float s2 = wave_sum(qn * kn[2048 + ib]) * 0.125f;
    float mx = fmaxf(s0, fmaxf(s1, s2));
    float e0 = __expf(s0 - mx), e1 = __expf(s1 - mx), e2 = __expf(s2 - mx);
    float inv = 1.f / (e0 + e1 + e2);
    float o = (e0 * vv[ib] + e1 * vv[1024 + ib] + e2 * vv[2048 + ib]) * inv;
    orow[ib] = f2bf(o);
  }
}

extern "C" void kernel_launch(void* const* d_in, const int* in_sizes, int n_in,
                              void* d_out, int out_size, void* d_ws, size_t ws_size,
                              hipStream_t stream){
  const float* x    = (const float*)d_in[0];
  const float* cond = (const float*)d_in[1];
  const float* mew1 = (const float*)d_in[2];
  const float* meb1 = (const float*)d_in[3];
  const float* mew2 = (const float*)d_in[4];
  const float* meb2 = (const float*)d_in[5];
  const float* qw   = (const float*)d_in[6];
  const float* qb   = (const float*)d_in[7];
  const float* kvw  = (const float*)d_in[8];
  const float* kvb  = (const float*)d_in[9];
  const float* qnw  = (const float*)d_in[10];
  const float* knw  = (const float*)d_in[11];
  const float* ow   = (const float*)d_in[12];
  const float* ob   = (const float*)d_in[13];

  char* ws = (char*)d_ws;
  float*    emb    = (float*)(ws + 0);          // 16x512 f32
  float*    kvpart = (float*)(ws + 32768);      // 16x6144 f32
  float*    kn     = (float*)(ws + 425984);     // 3x1024 f32
  float*    vv     = (float*)(ws + 438272);     // 3x1024 f32
  ushort_t* qwt    = (ushort_t*)(ws + 450560);  // [1024][3072] bf16
  ushort_t* owt    = (ushort_t*)(ws + 6742016); // [3072][1024] bf16
  ushort_t* Qbuf   = (ushort_t*)(ws + 13033472);// [10560][1024] bf16
  ushort_t* Obuf   = (ushort_t*)(ws + 34660352);// [10560][1024] bf16

  // xb (bf16 x) lives in d_out's 130MB region: only needed until the Q-GEMM;
  // the final GEMM fully overwrites d_out afterwards. No extra ws needed.
  ushort_t* xb = (ushort_t*)d_out;

  k_pre<<<1, 1024, 0, stream>>>(cond, mew1, meb1, mew2, meb2, emb);
  k_kv<<<384, 256, 0, stream>>>(emb, kvw, kvpart);
  k_knorm<<<1, 256, 0, stream>>>(kvpart, kvb, knw, kn, vv);
  k_tconv<<<3072, 256, 0, stream>>>(qw, qwt, 3072, 1024);
  k_tconv<<<3072, 256, 0, stream>>>(ow, owt, 1024, 3072);
  k_xconv<<<2048, 256, 0, stream>>>(x, xb, (TOK * CIMG) / 4);
  gemm_lds<0><<<83 * 8, 256, 0, stream>>>(xb, qwt, TOK, CIMG, KHD, qb, nullptr, Qbuf);
  k_attn<<<2640, 256, 0, stream>>>(Qbuf, kn, vv, qnw, Obuf);
  gemm_lds<1><<<83 * 24, 256, 0, stream>>>(Obuf, owt, TOK, KHD, CIMG, ob, x, d_out);
}